// Round 11
// baseline (114.103 us; speedup 1.0000x reference)
//
#include <hip/hip_runtime.h>

// MLP: 64 × (Linear(5,5)+ReLU) then Linear(5,1), BATCH = 1048576 rows.
// R19: R17 with ROWS=2 @ 8 waves/SIMD — the TLP experiment.
//
// R18 post-mortem: 3× fewer SMEM requests (2× s_load_dwordx16) was a
// slight REGRESSION (46.1 -> 47.6 µs). Ledger: packed VALU-busy pinned
// at ~29.5 µs; the ~17 µs idle is invariant to wait placement (R17),
// prefetch structure (R16), and request count (R18). The one thing all
// SMEM rounds shared: 4 waves/SIMD. Each wave computes only ~140 own
// cycles between lgkmcnt(0) waits; with 4 correlated waves the SIMD
// idles whenever all four are in a wait window — a COVERAGE problem,
// which explains why shrinking/moving the waits didn't help.
//
// Fix: ROWS=2, launch_bounds(256,8): 8192 waves -> 8 waves/SIMD.
// Per-wave phase ~70 cyc (25 pk_fma + 5 pk_max + 5 bias movs); waits
// come 2× as often but 8 hiders cover them. Total VALU work +~8% (bias
// movs amortized over 2 rows). Weight path reverted to R17's direct
// constant-AS s_loads (best measured form; one variable changed).
//
// Pre-committed read: ~33-38 µs @ 80-90% busy => TLP was the missing
// piece; ~46 µs => compute-minimal + wait-optimal + TLP-saturated all
// at one wall -> structural (clock/SMEM serialization), declare
// roofline on the best form.

#define MLP_DEPTH 64
#define MLP_D 5
#define ROWS 2

typedef float f2 __attribute__((ext_vector_type(2)));
// Constant-address-space pointer: uniform loads select as s_load (SMEM).
typedef const float __attribute__((address_space(4)))* cfp;

static __device__ __forceinline__ f2 splat2(float v) {
    f2 r; r.x = v; r.y = v; return r;
}

struct WB { float W[25]; float b[MLP_D]; };

static __device__ __forceinline__ void loadWB(WB& s, cfp cWs, cfp cbs, int l) {
    const cfp w = cWs + l * 25;
    const cfp bb = cbs + l * MLP_D;
#pragma unroll
    for (int k = 0; k < 25; ++k) s.W[k] = w[k];
#pragma unroll
    for (int j = 0; j < MLP_D; ++j) s.b[j] = bb[j];
}

// Force the compiler's lgkmcnt(0) wait HERE (SMEM waits are
// all-or-nothing): reading one SGPR of S drains S's s_loads at this
// point, before the next prefetch issues. "memory" + sched_barrier keep
// later s_loads from hoisting above.
#define TOUCH(S)                                                  \
    do {                                                          \
        asm volatile("" ::"s"((S).W[24]) : "memory");             \
        __builtin_amdgcn_sched_barrier(0);                        \
    } while (0)

// Packed row-fused layer: 1 row-pair × 5 outputs = 5 independent
// pk_fma chains; each half-lane runs the exact fmaf chain of all prior
// rounds (absmax must stay 0.0). Weights are wave-uniform SGPRs
// (v_pk_fma_f32: one SGPR source via op_sel splat; bias costs 5
// one-time v_movs per layer).
static __device__ __forceinline__ void computeWB(const WB& s, f2 h2[MLP_D]) {
    f2 acc[MLP_D];
#pragma unroll
    for (int j = 0; j < MLP_D; ++j)
        acc[j] = __builtin_elementwise_fma(
            h2[0], splat2(s.W[j * MLP_D + 0]), splat2(s.b[j]));
#pragma unroll
    for (int i = 1; i < MLP_D; ++i)
#pragma unroll
        for (int j = 0; j < MLP_D; ++j)
            acc[j] = __builtin_elementwise_fma(
                h2[i], splat2(s.W[j * MLP_D + i]), acc[j]);
#pragma unroll
    for (int j = 0; j < MLP_D; ++j)
        h2[j] = __builtin_elementwise_max(acc[j], splat2(0.0f));
}

__global__ __launch_bounds__(256, 8) void MLP_89687507075104_kernel(
    const float* __restrict__ x,      // [n, 5]
    const float* __restrict__ Ws,     // [64, 5, 5]
    const float* __restrict__ bs,     // [64, 5]
    const float* __restrict__ W_out,  // [1, 5]
    const float* __restrict__ b_out,  // [1]
    float* __restrict__ out,          // [n]
    int n)
{
    const cfp cWs = (cfp)(unsigned long long)Ws;
    const cfp cbs = (cfp)(unsigned long long)bs;
    const cfp cWo = (cfp)(unsigned long long)W_out;
    const cfp cbo = (cfp)(unsigned long long)b_out;

    const int t = blockIdx.x * blockDim.x + threadIdx.x;
    const long row0 = (long)t * ROWS;
    if (row0 >= n) return;

    // rows row0..row0+1 = 10 contiguous floats (40 B, 8B-aligned):
    // five dwordx2 loads.
    const float2* xp = reinterpret_cast<const float2*>(x + row0 * MLP_D);
    const float2 q0 = xp[0], q1 = xp[1], q2 = xp[2], q3 = xp[3], q4 = xp[4];
    // h2[i] = (h[row0][i], h[row0+1][i]) — row pair in register pairs.
    f2 h2[MLP_D];
    h2[0].x = q0.x; h2[1].x = q0.y; h2[2].x = q1.x; h2[3].x = q1.y; h2[4].x = q2.x;
    h2[0].y = q2.y; h2[1].y = q3.x; h2[2].y = q3.y; h2[3].y = q4.x; h2[4].y = q4.y;

    WB A, B;
    loadWB(A, cWs, cbs, 0);
    TOUCH(A);  // drain A(0) before loadB(1) issues: loop body stays clean

#pragma unroll 1
    for (int l = 0; l < MLP_DEPTH; l += 2) {
        loadWB(B, cWs, cbs, l + 1);     // issue; lands during computeA
        computeWB(A, h2);
        TOUCH(B);                       // wait B here (only B in flight)
        // Clamp keeps the final (redundant) prefetch in-bounds.
        const int ln = (l + 2 < MLP_DEPTH) ? (l + 2) : (MLP_DEPTH - 1);
        loadWB(A, cWs, cbs, ln);        // issue; lands during computeB
        computeWB(B, h2);
        TOUCH(A);                       // wait A here (only A in flight)
    }

    // Output layer: Linear(5,1) — packed (1 pk_fma chain), SGPR weights.
    const float wo0 = cWo[0], wo1 = cWo[1], wo2 = cWo[2], wo3 = cWo[3];
    const float wo4 = cWo[4], bo = cbo[0];
    f2 acc = __builtin_elementwise_fma(h2[0], splat2(wo0), splat2(bo));
    acc = __builtin_elementwise_fma(h2[1], splat2(wo1), acc);
    acc = __builtin_elementwise_fma(h2[2], splat2(wo2), acc);
    acc = __builtin_elementwise_fma(h2[3], splat2(wo3), acc);
    acc = __builtin_elementwise_fma(h2[4], splat2(wo4), acc);
    float2 ov;
    ov.x = acc.x; ov.y = acc.y;
    *reinterpret_cast<float2*>(out + row0) = ov;
}

extern "C" void kernel_launch(void* const* d_in, const int* in_sizes, int n_in,
                              void* d_out, int out_size, void* d_ws, size_t ws_size,
                              hipStream_t stream) {
    const float* x     = (const float*)d_in[0];
    const float* Ws    = (const float*)d_in[1];
    const float* bs    = (const float*)d_in[2];
    const float* W_out = (const float*)d_in[3];
    const float* b_out = (const float*)d_in[4];
    float* out = (float*)d_out;

    const int n = in_sizes[0] / MLP_D;  // batch rows (1048576)
    const int block = 256;
    const int threads_needed = (n + ROWS - 1) / ROWS;
    const int grid = (threads_needed + block - 1) / block;  // 2048
    MLP_89687507075104_kernel<<<grid, block, 0, stream>>>(
        x, Ws, bs, W_out, b_out, out, n);
}

// Round 12
// 107.154 us; speedup vs baseline: 1.0649x; 1.0649x over previous
//
#include <hip/hip_runtime.h>

// MLP: 64 × (Linear(5,5)+ReLU) then Linear(5,1), BATCH = 1048576 rows.
// R20: REVERT to R17 — the measured-best form (46.1 µs dispatch).
//
// Final model (fits all 12 rounds): v_pk_fma_f32 on gfx950 is issue
// compression only, NOT extra FLOPs — spec fp32 peak 157.3 TF is
// exactly 1 FMA/lane/cycle at 2.4 GHz (no packed doubling, unlike
// gfx90a). A pk op issues in 2 cyc, occupies the fp32 pipe 4 cyc;
// VALUBusy counts ISSUE cycles, so packed variants read ~63% with the
// pipe saturated. Pipe floor = (1.678e9 fma + 0.336e9 max)/32768 lanes
// = 61,440 cyc/SIMD; R8 scalar: 71.7k cyc @ 51.2 µs => 1.40 GHz;
// R17 packed: 64.0k cyc @ 46.1 µs => 1.39 GHz — same sustained clock,
// both pipe-bound. R19 (8 waves/SIMD) regressed to 55.5 µs at the SAME
// 63% issue-busy: more waves -> more power -> lower clock; TLP theory
// dead. Remaining levers (bias movs 4%, overhead 2%) are inside noise.
//
// Structure (= R17): weights via constant-AS s_load into SGPRs (zero
// DS, zero VALU on the weight path; v_pk_fma takes the SGPR directly
// via op_sel splat), A/B double-buffered one layer ahead, TOUCH forcing
// each lgkmcnt(0) where only the finished set is outstanding, packed
// row-pair compute (ROWS=4 -> 2 pairs × 5 independent pk chains).

#define MLP_DEPTH 64
#define MLP_D 5
#define ROWS 4

typedef float f2 __attribute__((ext_vector_type(2)));
// Constant-address-space pointer: uniform loads select as s_load (SMEM).
typedef const float __attribute__((address_space(4)))* cfp;

static __device__ __forceinline__ f2 splat2(float v) {
    f2 r; r.x = v; r.y = v; return r;
}

struct WB { float W[25]; float b[MLP_D]; };

static __device__ __forceinline__ void loadWB(WB& s, cfp cWs, cfp cbs, int l) {
    const cfp w = cWs + l * 25;
    const cfp bb = cbs + l * MLP_D;
#pragma unroll
    for (int k = 0; k < 25; ++k) s.W[k] = w[k];
#pragma unroll
    for (int j = 0; j < MLP_D; ++j) s.b[j] = bb[j];
}

// Force the compiler's lgkmcnt(0) wait HERE (SMEM waits are
// all-or-nothing): reading one SGPR of S drains S's s_loads at this
// point, before the next prefetch issues. "memory" + sched_barrier keep
// later s_loads from hoisting above.
#define TOUCH(S)                                                  \
    do {                                                          \
        asm volatile("" ::"s"((S).W[24]) : "memory");             \
        __builtin_amdgcn_sched_barrier(0);                        \
    } while (0)

// Packed row-fused layer: 2 row-pairs × 5 outputs = 10 independent
// pk_fma chains; each half-lane runs the exact fmaf chain of all prior
// rounds (absmax must stay 0.0). Weights/bias are wave-uniform SGPRs
// (v_pk_fma_f32 takes one SGPR source via op_sel splat; bias needs a
// one-time v_mov per layer, amortized over the row-pairs).
static __device__ __forceinline__ void computeWB(const WB& s, f2 h2[2][MLP_D]) {
#pragma unroll
    for (int p = 0; p < 2; ++p) {
        f2 acc[MLP_D];
#pragma unroll
        for (int j = 0; j < MLP_D; ++j)
            acc[j] = __builtin_elementwise_fma(
                h2[p][0], splat2(s.W[j * MLP_D + 0]), splat2(s.b[j]));
#pragma unroll
        for (int i = 1; i < MLP_D; ++i)
#pragma unroll
            for (int j = 0; j < MLP_D; ++j)
                acc[j] = __builtin_elementwise_fma(
                    h2[p][i], splat2(s.W[j * MLP_D + i]), acc[j]);
#pragma unroll
        for (int j = 0; j < MLP_D; ++j)
            h2[p][j] = __builtin_elementwise_max(acc[j], splat2(0.0f));
    }
}

__global__ __launch_bounds__(256, 4) void MLP_89687507075104_kernel(
    const float* __restrict__ x,      // [n, 5]
    const float* __restrict__ Ws,     // [64, 5, 5]
    const float* __restrict__ bs,     // [64, 5]
    const float* __restrict__ W_out,  // [1, 5]
    const float* __restrict__ b_out,  // [1]
    float* __restrict__ out,          // [n]
    int n)
{
    const cfp cWs = (cfp)(unsigned long long)Ws;
    const cfp cbs = (cfp)(unsigned long long)bs;
    const cfp cWo = (cfp)(unsigned long long)W_out;
    const cfp cbo = (cfp)(unsigned long long)b_out;

    const int t = blockIdx.x * blockDim.x + threadIdx.x;
    const long row0 = (long)t * ROWS;
    if (row0 >= n) return;

    // rows row0..row0+3 = 20 contiguous floats (80 B, 16B-aligned).
    const float4* xp = reinterpret_cast<const float4*>(x + row0 * MLP_D);
    const float4 q0 = xp[0], q1 = xp[1], q2 = xp[2], q3 = xp[3], q4 = xp[4];
    // h2[p][i] = (h[2p][i], h[2p+1][i]) — row-paired into register pairs.
    f2 h2[2][MLP_D];
    h2[0][0].x=q0.x; h2[0][1].x=q0.y; h2[0][2].x=q0.z; h2[0][3].x=q0.w; h2[0][4].x=q1.x;
    h2[0][0].y=q1.y; h2[0][1].y=q1.z; h2[0][2].y=q1.w; h2[0][3].y=q2.x; h2[0][4].y=q2.y;
    h2[1][0].x=q2.z; h2[1][1].x=q2.w; h2[1][2].x=q3.x; h2[1][3].x=q3.y; h2[1][4].x=q3.z;
    h2[1][0].y=q3.w; h2[1][1].y=q4.x; h2[1][2].y=q4.y; h2[1][3].y=q4.z; h2[1][4].y=q4.w;

    WB A, B;
    loadWB(A, cWs, cbs, 0);
    TOUCH(A);  // drain A(0) before loadB(1) issues: loop body stays clean

#pragma unroll 1
    for (int l = 0; l < MLP_DEPTH; l += 2) {
        loadWB(B, cWs, cbs, l + 1);     // issue; lands during computeA
        computeWB(A, h2);
        TOUCH(B);                       // wait B here (only B in flight)
        // Clamp keeps the final (redundant) prefetch in-bounds.
        const int ln = (l + 2 < MLP_DEPTH) ? (l + 2) : (MLP_DEPTH - 1);
        loadWB(A, cWs, cbs, ln);        // issue; lands during computeB
        computeWB(B, h2);
        TOUCH(A);                       // wait A here (only A in flight)
    }

    // Output layer: Linear(5,1) — packed (2 pk_fma chains), SGPR weights.
    const float wo0 = cWo[0], wo1 = cWo[1], wo2 = cWo[2], wo3 = cWo[3];
    const float wo4 = cWo[4], bo = cbo[0];
    f2 o2[2];
#pragma unroll
    for (int p = 0; p < 2; ++p) {
        f2 acc = __builtin_elementwise_fma(h2[p][0], splat2(wo0), splat2(bo));
        acc = __builtin_elementwise_fma(h2[p][1], splat2(wo1), acc);
        acc = __builtin_elementwise_fma(h2[p][2], splat2(wo2), acc);
        acc = __builtin_elementwise_fma(h2[p][3], splat2(wo3), acc);
        acc = __builtin_elementwise_fma(h2[p][4], splat2(wo4), acc);
        o2[p] = acc;
    }
    float4 ov;
    ov.x = o2[0].x; ov.y = o2[0].y; ov.z = o2[1].x; ov.w = o2[1].y;
    *reinterpret_cast<float4*>(out + row0) = ov;
}

extern "C" void kernel_launch(void* const* d_in, const int* in_sizes, int n_in,
                              void* d_out, int out_size, void* d_ws, size_t ws_size,
                              hipStream_t stream) {
    const float* x     = (const float*)d_in[0];
    const float* Ws    = (const float*)d_in[1];
    const float* bs    = (const float*)d_in[2];
    const float* W_out = (const float*)d_in[3];
    const float* b_out = (const float*)d_in[4];
    float* out = (float*)d_out;

    const int n = in_sizes[0] / MLP_D;  // batch rows (1048576)
    const int block = 256;
    const int threads_needed = (n + ROWS - 1) / ROWS;
    const int grid = (threads_needed + block - 1) / block;  // 1024
    MLP_89687507075104_kernel<<<grid, block, 0, stream>>>(
        x, Ws, bs, W_out, b_out, out, n);
}